// Round 12
// baseline (372.527 us; speedup 1.0000x reference)
//
#include <hip/hip_runtime.h>

typedef _Float16 f16;
typedef _Float16 half8 __attribute__((ext_vector_type(8)));
typedef _Float16 half4 __attribute__((ext_vector_type(4)));
typedef float f32x4 __attribute__((ext_vector_type(4)));

#define NN 2048
#define BB 32
#define CINC 32
#define HH 64
#define DD 64
#define C1 96      // CIN + H
#define KI 192     // 2 * C1
#define OG 128
#define OU 64

// xg element (n, ki, b) with ki = ks*32+kk, kk = q*8+kkl:
// flat = ((((n*6+ks)*4+q)*32 + b)*8 + kkl   -> wave loads are 16B-contiguous
#define XGI(n, ks, b, kk) \
  ((((((size_t)(n)) * 6 + (ks)) * 4 + ((kk) >> 3)) * BB + (b)) * 8 + ((kk) & 7))

__device__ __forceinline__ f32x4 mfma16(half8 a, half8 b, f32x4 c) {
  return __builtin_amdgcn_mfma_f32_16x16x32_f16(a, b, c, 0, 0, 0);
}

typedef __attribute__((address_space(1))) const void* gas_t;
typedef __attribute__((address_space(3))) void* las_t;
__device__ __forceinline__ void gl_lds16(const void* g, void* l) {
  __builtin_amdgcn_global_load_lds((gas_t)g, (las_t)l, 16, 0, 0);
}

// XOR swizzle for 128B-row LDS tiles (rule #21: pre-swizzled source + swizzled read)
#define SWZ(row, kb) (((row) << 7) + ((kb) ^ (((row) & 7) << 4)))

// ------- LayerNorm -> e (f16) + both bias projections, one launch -------
__global__ __launch_bounds__(256) void k_ln_bias(
    const float* __restrict__ ne, const float* __restrict__ te,
    const float* __restrict__ gg, const float* __restrict__ gb,
    const float* __restrict__ ug, const float* __restrict__ ub,
    const float* __restrict__ gbp, const float* __restrict__ ubp,
    f16* __restrict__ egh, f16* __restrict__ euh,
    float* __restrict__ biasg, float* __restrict__ biasu) {
  __shared__ float esg[4][64];
  __shared__ float esu[4][64];
  int nl = threadIdx.x >> 6;
  int node = blockIdx.x * 4 + nl;
  int d = threadIdx.x & 63;
  float v = ne[node * DD + d] + te[d];
  float s = v;
  #pragma unroll
  for (int m = 1; m < 64; m <<= 1) s += __shfl_xor(s, m, 64);
  float mu = s * (1.f / 64.f);
  float df = v - mu;
  float q = df * df;
  #pragma unroll
  for (int m = 1; m < 64; m <<= 1) q += __shfl_xor(q, m, 64);
  float rs = rsqrtf(q * (1.f / 64.f) + 1e-12f);
  float base = df * rs;
  float a = base * gg[d] + gb[d];
  float b = base * ug[d] + ub[d];
  egh[node * DD + d] = (f16)a;
  euh[node * DD + d] = (f16)b;
  esg[nl][d] = a; esu[nl][d] = b;
  __syncthreads();
  #pragma unroll
  for (int i = 0; i < 3; ++i) {
    int u = i * 256 + threadIdx.x;
    int un = u / 192, oo = u % 192;
    int n2 = blockIdx.x * 4 + un;
    float acc = 0.f;
    if (oo < OG) {
      #pragma unroll 8
      for (int dd = 0; dd < 64; ++dd) acc += esg[un][dd] * gbp[dd * OG + oo];
      biasg[(size_t)n2 * OG + oo] = acc;
    } else {
      int o = oo - OG;
      #pragma unroll 8
      for (int dd = 0; dd < 64; ++dd) acc += esu[un][dd] * ubp[dd * OU + o];
      biasu[(size_t)n2 * OU + o] = acc;
    }
  }
}

// ------- wpool (d,ki,o) f32 -> wt2: 2KB-contiguous MFMA A-tiles -------
// tile (h = o>>6, ks = ki>>5, T = (o&63)*2 + ((ki>>4)&1)); within: row kil = ki&15, col d.
// element addr = (((h*6+ks)*128 + T)*16 + kil)*64 + d
__global__ __launch_bounds__(256) void k_wpool_t(const float* __restrict__ gwp,
                                                 const float* __restrict__ uwp,
                                                 f16* __restrict__ wtg,
                                                 f16* __restrict__ wtu) {
  const int upd = blockIdx.z;
  if (upd && blockIdx.y >= OU / 16) return;
  const float* wpool = upd ? uwp : gwp;
  f16* wt = upd ? wtu : wtg;
  const int O = upd ? OU : OG;
  __shared__ float tile[64][17];
  int ki = blockIdx.x;
  int o0 = blockIdx.y * 16;
  int t = threadIdx.x;
  #pragma unroll
  for (int i = 0; i < 4; ++i) {
    int e2 = i * 256 + t;
    int d = e2 >> 4, o = e2 & 15;
    tile[d][o] = wpool[((size_t)d * KI + ki) * O + o0 + o];
  }
  __syncthreads();
  #pragma unroll
  for (int i = 0; i < 4; ++i) {
    int e2 = i * 256 + t;
    int o = e2 >> 6, d = e2 & 63;
    const int og = o0 + o;
    size_t row = (((size_t)(og >> 6) * 6 + (ki >> 5)) * 128 +
                  ((og & 63) * 2 + ((ki >> 4) & 1))) * 16 + (ki & 15);
    wt[row * DD + d] = (f16)tile[d][o];
  }
}

// ------- build cm[b][c][m], xg (c<96), xg2 x-part, sth[b][m][o] in one pass -------
__global__ __launch_bounds__(256) void k_build_inp(const float* __restrict__ x,
                                                   const float* __restrict__ st,
                                                   f16* __restrict__ cm,
                                                   f16* __restrict__ xg,
                                                   f16* __restrict__ xg2,
                                                   f16* __restrict__ sth) {
  __shared__ f16 tile[96][66];
  int mb = blockIdx.x * 64;
  int b = blockIdx.y;
  int t = threadIdx.x;
  #pragma unroll
  for (int i = 0; i < 24; ++i) {
    int e2 = i * 256 + t;  // 0..6143
    int m = e2 / 96, c = e2 % 96;
    float v = (c < CINC) ? x[((size_t)b * NN + mb + m) * CINC + c]
                         : st[((size_t)b * NN + mb + m) * HH + c - CINC];
    f16 h = (f16)v;
    tile[c][m] = h;
    xg[XGI(mb + m, c >> 5, b, c & 31)] = h;
    if (c < CINC) xg2[XGI(mb + m, 0, b, c)] = h;
    else sth[((size_t)b * NN + mb + m) * HH + c - CINC] = h;
  }
  __syncthreads();
  #pragma unroll
  for (int i = 0; i < 24; ++i) {
    int e2 = i * 256 + t;
    int c = e2 >> 6, m = e2 & 63;
    cm[((size_t)b * C1 + c) * NN + mb + m] = tile[c][m];
  }
}

// ---------------- zs[b][m][o] -> cand_cm[b][32+o][m] ----------------
__global__ __launch_bounds__(256) void k_transpose_zs(const f16* __restrict__ zs,
                                                      f16* __restrict__ cm) {
  __shared__ f16 tile[64][66];
  int mb = blockIdx.x * 64;
  int b = blockIdx.y;
  int t = threadIdx.x;
  #pragma unroll
  for (int i = 0; i < 16; ++i) {
    int e2 = i * 256 + t;
    int m = e2 >> 6, o = e2 & 63;
    tile[o][m] = zs[((size_t)b * NN + mb + m) * HH + o];
  }
  __syncthreads();
  #pragma unroll
  for (int i = 0; i < 16; ++i) {
    int e2 = i * 256 + t;
    int o = e2 >> 6, m = e2 & 63;
    cm[((size_t)b * C1 + CINC + o) * NN + mb + m] = tile[o][m];
  }
}

// ------- fused scores+softmax: adj[r][:] = softmax(e[r] . e^T); y selects gate/update -------
__global__ __launch_bounds__(256) void k_attn(const f16* __restrict__ eg,
                                              const f16* __restrict__ eu,
                                              f16* __restrict__ adjg,
                                              f16* __restrict__ adju) {
  const f16* eh = blockIdx.y ? eu : eg;
  f16* adj = blockIdx.y ? adju : adjg;
  const int r0 = blockIdx.x * 16;
  const int w = threadIdx.x >> 6, lane = threadIdx.x & 63;
  const int fr = lane & 15, fq = lane >> 4;
  __shared__ float pm[4][16], ps[4][16];
  __shared__ float fm[16], fs[16];
  const half8 a0 = *(const half8*)&eh[(size_t)(r0 + fr) * DD + fq * 8];
  const half8 a1 = *(const half8*)&eh[(size_t)(r0 + fr) * DD + 32 + fq * 8];
  float m[4], s[4];
  #pragma unroll
  for (int r = 0; r < 4; ++r) { m[r] = -3.0e38f; s[r] = 0.f; }
  for (int ct = 0; ct < 32; ++ct) {
    const int c0 = w * 512 + ct * 16;
    half8 b0 = *(const half8*)&eh[(size_t)(c0 + fr) * DD + fq * 8];
    half8 b1 = *(const half8*)&eh[(size_t)(c0 + fr) * DD + 32 + fq * 8];
    f32x4 d = mfma16(a0, b0, f32x4{0.f, 0.f, 0.f, 0.f});
    d = mfma16(a1, b1, d);
    #pragma unroll
    for (int r = 0; r < 4; ++r) {
      float mn = fmaxf(m[r], d[r]);
      s[r] = s[r] * __expf(m[r] - mn) + __expf(d[r] - mn);
      m[r] = mn;
    }
  }
  #pragma unroll
  for (int r = 0; r < 4; ++r) {
    #pragma unroll
    for (int mk = 1; mk < 16; mk <<= 1) {
      float mo = __shfl_xor(m[r], mk, 64);
      float so = __shfl_xor(s[r], mk, 64);
      float mn = fmaxf(m[r], mo);
      s[r] = s[r] * __expf(m[r] - mn) + so * __expf(mo - mn);
      m[r] = mn;
    }
  }
  if (fr == 0) {
    #pragma unroll
    for (int r = 0; r < 4; ++r) { pm[w][fq * 4 + r] = m[r]; ps[w][fq * 4 + r] = s[r]; }
  }
  __syncthreads();
  if (threadIdx.x < 16) {
    float M = -3.0e38f;
    #pragma unroll
    for (int i = 0; i < 4; ++i) M = fmaxf(M, pm[i][threadIdx.x]);
    float S = 0.f;
    #pragma unroll
    for (int i = 0; i < 4; ++i) S += ps[i][threadIdx.x] * __expf(pm[i][threadIdx.x] - M);
    fm[threadIdx.x] = M; fs[threadIdx.x] = 1.f / S;
  }
  __syncthreads();
  float Mr[4], Sr[4];
  #pragma unroll
  for (int r = 0; r < 4; ++r) { Mr[r] = fm[fq * 4 + r]; Sr[r] = fs[fq * 4 + r]; }
  for (int ct = 0; ct < 32; ++ct) {
    const int c0 = w * 512 + ct * 16;
    half8 b0 = *(const half8*)&eh[(size_t)(c0 + fr) * DD + fq * 8];
    half8 b1 = *(const half8*)&eh[(size_t)(c0 + fr) * DD + 32 + fq * 8];
    f32x4 d = mfma16(a0, b0, f32x4{0.f, 0.f, 0.f, 0.f});
    d = mfma16(a1, b1, d);
    #pragma unroll
    for (int r = 0; r < 4; ++r)
      adj[(size_t)(r0 + fq * 4 + r) * NN + c0 + fr] = (f16)(__expf(d[r] - Mr[r]) * Sr[r]);
  }
}

// ---------------- xa: out_xg (ki=96+l) = adj(n,m) @ cm(b*96+l, m)^T ----------------
#define BM 64
#define BN 96

__global__ __launch_bounds__(256, 4) void k_gemm_xa(const f16* __restrict__ A,
                                                    const f16* __restrict__ Bm,
                                                    f16* __restrict__ xg) {
  const int orig = blockIdx.x;          // 0..1023
  const int xcd = orig & 7, j = orig >> 3;
  const int nb = (j >> 2) * BM;
  const int by = (xcd << 2) + (j & 3);  // 4 consecutive by per XCD
  const int cb = by * BN;
  const int tid = threadIdx.x;
  const int w = tid >> 6, lane = tid & 63;
  const int wr = (w >> 1) * 32, wc = (w & 1) * 48;
  const int fr = lane & 15, fq = lane >> 4;

  const int arow = tid >> 3;                               // 0..31
  const int acolb = ((tid & 7) * 16) ^ ((arow & 7) << 4);  // pre-swizzled, j-invariant
  const char* asrc = (const char*)A + (size_t)(nb + arow) * (NN * 2) + acolb;
  const char* bsrc = (const char*)Bm + (size_t)(cb + arow) * (NN * 2) + acolb;

  __shared__ f16 Al[2][BM * 64];
  __shared__ f16 Bl[2][BN * 64];
  auto stage = [&](int buf, int kt) {   // 5 x global_load_lds per wave
    const size_t ko = (size_t)kt * 2;
    char* ad = (char*)&Al[buf][0] + (w << 10);
    char* bd = (char*)&Bl[buf][0] + (w << 10);
    gl_lds16(asrc + ko, ad);
    gl_lds16(asrc + ko + (size_t)32 * (NN * 2), ad + 4096);
    gl_lds16(bsrc + ko, bd);
    gl_lds16(bsrc + ko + (size_t)32 * (NN * 2), bd + 4096);
    gl_lds16(bsrc + ko + (size_t)64 * (NN * 2), bd + 8192);
  };

  f32x4 acc[2][3] = {};
  stage(0, 0);
  for (int kt = 0; kt < NN; kt += 64) {
    const int cur = (kt >> 6) & 1;
    if (kt + 64 < NN) {
      stage(cur ^ 1, kt + 64);
      asm volatile("s_waitcnt vmcnt(5)" ::: "memory");   // my stage(cur) landed
    } else {
      asm volatile("s_waitcnt vmcnt(0)" ::: "memory");
    }
    __builtin_amdgcn_sched_barrier(0);
    __builtin_amdgcn_s_barrier();                         // A: buf[cur] ready (all waves)
    const char* Ab = (const char*)&Al[cur][0];
    const char* Bb = (const char*)&Bl[cur][0];
    half8 af[2][2], bf[2][3];
    #pragma unroll
    for (int k0 = 0; k0 < 2; ++k0) {
      const int kb = k0 * 64 + fq * 16;
      #pragma unroll
      for (int mt = 0; mt < 2; ++mt)
        af[k0][mt] = *(const half8*)(Ab + SWZ(wr + mt * 16 + fr, kb));
      #pragma unroll
      for (int nt = 0; nt < 3; ++nt)
        bf[k0][nt] = *(const half8*)(Bb + SWZ(wc + nt * 16 + fr, kb));
    }
    asm volatile("s_waitcnt lgkmcnt(0)" ::: "memory");    // my reads of buf[cur] done
    __builtin_amdgcn_sched_barrier(0);
    __builtin_amdgcn_s_barrier();                         // B: release buf[cur] for restage
    #pragma unroll
    for (int k0 = 0; k0 < 2; ++k0)
      #pragma unroll
      for (int mt = 0; mt < 2; ++mt)
        #pragma unroll
        for (int nt = 0; nt < 3; ++nt)
          acc[mt][nt] = mfma16(af[k0][mt], bf[k0][nt], acc[mt][nt]);
  }
  #pragma unroll
  for (int mt = 0; mt < 2; ++mt)
    #pragma unroll
    for (int nt = 0; nt < 3; ++nt)
      #pragma unroll
      for (int r = 0; r < 4; ++r) {
        int n = nb + wr + mt * 16 + fq * 4 + r;
        int l = wc + nt * 16 + fr;         // 0..95 -> ki = 96+l
        xg[XGI(n, 3 + (l >> 5), by, l & 31)] = (f16)acc[mt][nt][r];
      }
}

// ---------------- fused W-gen + apply (W never touches HBM) ----------------
// Block: 16 nodes x 64 o-cols x full KI. Per ks-chunk: W-gen into 64KB LDS via MFMA
// (wt tiles = A, e nodes = B), barrier, apply MFMA (xg rows = A, Wc = B), barrier.
// Wc swizzle S(a) = a ^ ((((a>>12)^(a>>6))&7)<<4) — write spread on node, read on o.
// GATE: y=0 -> z-outputs (zs + xg2 z-slice), y=1 -> r-outputs (rbuf).
// !GATE: final out = r*state + (1-r)*tanh.
template <bool GATE>
__global__ __launch_bounds__(256, 1) void k_wap(
    const f16* __restrict__ eh, const f16* __restrict__ wt2,
    const f16* __restrict__ xgr,
    const float* __restrict__ bias,
    const f16* __restrict__ sth,
    f16* __restrict__ xg2, f16* __restrict__ zs, f16* __restrict__ rbuf,
    float* __restrict__ outp) {
  __shared__ __align__(128) char Wc[16 * 4096];   // 64 KB
  const int nodebase = blockIdx.x * 16;
  const int half = GATE ? blockIdx.y : 0;
  const int tid = threadIdx.x;
  const int w = tid >> 6, lane = tid & 63;
  const int fr = lane & 15, fq = lane >> 4;

  // e B-frags: col = node (fr), K = d
  const half8 e0 = *(const half8*)&eh[(size_t)(nodebase + fr) * DD + fq * 8];
  const half8 e1 = *(const half8*)&eh[(size_t)(nodebase + fr) * DD + 32 + fq * 8];

  const char* wbase = (const char*)wt2 + (size_t)half * 6 * 128 * 2048;

  f32x4 acc[4][2][4] = {};   // [node j][mt(b)][ot(o)]

  for (int ks = 0; ks < 6; ++ks) {
    const char* cbase = wbase + (size_t)ks * 128 * 2048 + fr * 128 + fq * 16;
    // ---- W-gen: 32 tiles/wave, groups of 8, double-buffered register loads ----
    half8 sa[2][8][2];
    #pragma unroll
    for (int j = 0; j < 8; ++j) {
      const char* p = cbase + (size_t)(w * 32 + j) * 2048;
      sa[0][j][0] = *(const half8*)p;
      sa[0][j][1] = *(const half8*)(p + 64);
    }
    #pragma unroll
    for (int g = 0; g < 4; ++g) {
      const int cur = g & 1;
      if (g < 3) {
        #pragma unroll
        for (int j = 0; j < 8; ++j) {
          const char* p = cbase + (size_t)(w * 32 + (g + 1) * 8 + j) * 2048;
          sa[cur ^ 1][j][0] = *(const half8*)p;
          sa[cur ^ 1][j][1] = *(const half8*)(p + 64);
        }
      }
      __builtin_amdgcn_sched_barrier(0);    // loads stay issued before compute
      #pragma unroll
      for (int j = 0; j < 8; ++j) {
        const int T = w * 32 + g * 8 + j;
        const int o_local = T >> 1, khalf = T & 1;
        f32x4 d = mfma16(sa[cur][j][0], e0, f32x4{0.f, 0.f, 0.f, 0.f});
        d = mfma16(sa[cur][j][1], e1, d);
        half4 h4;
        #pragma unroll
        for (int r = 0; r < 4; ++r) h4[r] = (f16)d[r];
        int a = (fr << 12) + o_local * 64 + khalf * 32 + fq * 8;
        a ^= (((fr ^ o_local) & 7) << 4);
        *(half4*)(Wc + a) = h4;
      }
    }
    __syncthreads();                        // Wc[ks] complete
    // ---- apply: wave w consumes nodes 4w..4w+3 ----
    half8 af[4][2];
    #pragma unroll
    for (int j2 = 0; j2 < 4; ++j2) {
      const int n = nodebase + w * 4 + j2;
      af[j2][0] = *(const half8*)&xgr[XGI(n, ks, fr, fq * 8)];
      af[j2][1] = *(const half8*)&xgr[XGI(n, ks, 16 + fr, fq * 8)];
    }
    __builtin_amdgcn_sched_barrier(0);
    #pragma unroll
    for (int j2 = 0; j2 < 4; ++j2) {
      const int nd = w * 4 + j2;
      #pragma unroll
      for (int ot = 0; ot < 4; ++ot) {
        const int ol = ot * 16 + fr;
        int a = (nd << 12) + ol * 64 + fq * 16;
        a ^= (((nd ^ ol) & 7) << 4);
        half8 bf = *(const half8*)(Wc + a);
        acc[j2][0][ot] = mfma16(af[j2][0], bf, acc[j2][0][ot]);
        acc[j2][1][ot] = mfma16(af[j2][1], bf, acc[j2][1][ot]);
      }
    }
    __syncthreads();                        // release Wc for next chunk
  }
  // ---- epilogue ----
  #pragma unroll
  for (int j2 = 0; j2 < 4; ++j2) {
    const int n = nodebase + w * 4 + j2;
    #pragma unroll
    for (int ot = 0; ot < 4; ++ot) {
      const int o = half * 64 + ot * 16 + fr;
      const float bs = bias[(size_t)n * (GATE ? OG : OU) + o];
      #pragma unroll
      for (int mt = 0; mt < 2; ++mt)
        #pragma unroll
        for (int r = 0; r < 4; ++r) {
          const int b = mt * 16 + fq * 4 + r;
          const float val = acc[j2][mt][ot][r] + bs;
          if (GATE) {
            const float s = 1.f / (1.f + expf(-val));
            if (half == 0) {                // z-half
              const size_t bno = ((size_t)b * NN + n) * HH + o;
              const float zst = s * (float)sth[bno];
              xg2[XGI(n, 1 + (o >> 5), b, o & 31)] = (f16)zst;  // ki = 32+o
              zs[bno] = (f16)zst;
            } else {                        // r-half
              rbuf[((size_t)b * NN + n) * HH + (o - HH)] = (f16)s;
            }
          } else {
            const size_t bno = ((size_t)b * NN + n) * HH + o;
            const float hc = tanhf(val);
            const float rr = (float)rbuf[bno];
            outp[bno] = rr * (float)sth[bno] + (1.f - rr) * hc;
          }
        }
    }
  }
}

extern "C" void kernel_launch(void* const* d_in, const int* in_sizes, int n_in,
                              void* d_out, int out_size, void* d_ws, size_t ws_size,
                              hipStream_t stream) {
  const float* x   = (const float*)d_in[0];
  const float* st  = (const float*)d_in[1];
  const float* ne  = (const float*)d_in[2];
  const float* te  = (const float*)d_in[3];
  const float* gwp = (const float*)d_in[4];
  const float* gbp = (const float*)d_in[5];
  const float* gg  = (const float*)d_in[6];
  const float* gb  = (const float*)d_in[7];
  const float* uwp = (const float*)d_in[8];
  const float* ubp = (const float*)d_in[9];
  const float* ug  = (const float*)d_in[10];
  const float* ub  = (const float*)d_in[11];
  float* out = (float*)d_out;

  char* wsb = (char*)d_ws;
  size_t off = 0;
  auto alloc = [&](size_t bytes) {
    char* p = wsb + off;
    off = (off + bytes + 255) & ~(size_t)255;
    return p;
  };
  f16*   egh   = (f16*)  alloc((size_t)NN * DD * 2);
  f16*   euh   = (f16*)  alloc((size_t)NN * DD * 2);
  float* biasg = (float*)alloc((size_t)NN * OG * 4);
  float* biasu = (float*)alloc((size_t)NN * OU * 4);
  f16*   wtg   = (f16*)  alloc((size_t)OG * KI * DD * 2);   //  3 MB
  f16*   wtu   = (f16*)  alloc((size_t)OU * KI * DD * 2);   // 1.5 MB
  f16*   xg    = (f16*)  alloc((size_t)NN * BB * KI * 2);   // 24 MB
  f16*   xg2   = (f16*)  alloc((size_t)NN * BB * KI * 2);   // 24 MB
  f16*   cm    = (f16*)  alloc((size_t)BB * C1 * NN * 2);   // 12 MB
  f16*   zs    = (f16*)  alloc((size_t)BB * NN * HH * 2);   //  8 MB
  f16*   rbuf  = (f16*)  alloc((size_t)BB * NN * HH * 2);   //  8 MB
  f16*   sth   = (f16*)  alloc((size_t)BB * NN * HH * 2);   //  8 MB
  f16*   adj   = (f16*)  alloc((size_t)NN * NN * 2);        //  8 MB
  f16*   adju  = (f16*)  alloc((size_t)NN * NN * 2);        //  8 MB
  (void)ws_size; (void)in_sizes; (void)n_in; (void)out_size;

  hipLaunchKernelGGL(k_ln_bias, dim3(NN / 4), dim3(256), 0, stream,
                     ne, te, gg, gb, ug, ub, gbp, ubp,
                     egh, euh, biasg, biasu);
  hipLaunchKernelGGL(k_wpool_t, dim3(KI, OG / 16, 2), dim3(256), 0, stream,
                     gwp, uwp, wtg, wtu);
  hipLaunchKernelGGL(k_build_inp, dim3(NN / 64, BB), dim3(256), 0, stream,
                     x, st, cm, xg, xg2, sth);
  hipLaunchKernelGGL(k_attn, dim3(NN / 16, 2), dim3(256), 0, stream,
                     egh, euh, adj, adju);

  // ---- gate GCN ----
  hipLaunchKernelGGL(k_gemm_xa, dim3(1024), dim3(256), 0, stream, adj, cm, xg);
  hipLaunchKernelGGL((k_wap<true>), dim3(NN / 16, 2), dim3(256), 0, stream,
                     egh, wtg, xg, biasg, sth, xg2, zs, rbuf, (float*)nullptr);
  hipLaunchKernelGGL(k_transpose_zs, dim3(NN / 64, BB), dim3(256), 0, stream, zs, cm);

  // ---- update GCN ----
  hipLaunchKernelGGL(k_gemm_xa, dim3(1024), dim3(256), 0, stream, adju, cm, xg2);
  hipLaunchKernelGGL((k_wap<false>), dim3(NN / 16, 1), dim3(256), 0, stream,
                     euh, wtu, xg2, biasu, sth, (f16*)nullptr, (f16*)nullptr, rbuf, out);
}

// Round 13
// 192.265 us; speedup vs baseline: 1.9376x; 1.9376x over previous
//
#include <hip/hip_runtime.h>

typedef _Float16 f16;
typedef _Float16 half8 __attribute__((ext_vector_type(8)));
typedef float f32x4 __attribute__((ext_vector_type(4)));

#define NN 2048
#define BB 32
#define CINC 32
#define HH 64
#define DD 64
#define C1 96      // CIN + H
#define KI 192     // 2 * C1
#define OG 128
#define OU 64
#define WCG 24576  // OG * KI
#define WCU 12288  // OU * KI

// xg layout: [n][ks][b][kk]  (ks = ki>>5, kk = ki&31)
#define XGI(n, ks, b, kk) (((((size_t)(n)) * 6 + (ks)) * BB + (b)) * 32 + (kk))
// node-major state/gate buffers: [n][b][h]
#define STHI(n, b, o) ((((size_t)(n)) * BB + (b)) * HH + (o))

__device__ __forceinline__ f32x4 mfma16(half8 a, half8 b, f32x4 c) {
  return __builtin_amdgcn_mfma_f32_16x16x32_f16(a, b, c, 0, 0, 0);
}

typedef __attribute__((address_space(1))) const void* gas_t;
typedef __attribute__((address_space(3))) void* las_t;
__device__ __forceinline__ void gl_lds16(const void* g, void* l) {
  __builtin_amdgcn_global_load_lds((gas_t)g, (las_t)l, 16, 0, 0);
}

// XOR swizzle for 128B-row LDS tiles (rule #21: pre-swizzled source + swizzled read)
#define SWZ(row, kb) (((row) << 7) + ((kb) ^ (((row) & 7) << 4)))

// ---------------- merged prep: ln+bias | wpool_t | build_inp ----------------
// grid.x = 512 (ln) + 2304 (wpool: 192 ki x 12 o-blocks) + 1024 (build: 32 mb x 32 b)
__global__ __launch_bounds__(256) void k_prep(
    const float* __restrict__ ne, const float* __restrict__ te,
    const float* __restrict__ gg, const float* __restrict__ gb,
    const float* __restrict__ ug, const float* __restrict__ ub,
    const float* __restrict__ gbp, const float* __restrict__ ubp,
    const float* __restrict__ gwp, const float* __restrict__ uwp,
    const float* __restrict__ x, const float* __restrict__ st,
    f16* __restrict__ egh, f16* __restrict__ euh,
    float* __restrict__ biasg, float* __restrict__ biasu,
    f16* __restrict__ wtg, f16* __restrict__ wtu,
    f16* __restrict__ cm, f16* __restrict__ xg, f16* __restrict__ sth) {
  __shared__ __align__(16) char smem[12672];
  const int bid = blockIdx.x;
  const int t = threadIdx.x;
  if (bid < 512) {
    // ---------- ln + bias ----------
    float (*esg)[64] = (float(*)[64])smem;
    float (*esu)[64] = (float(*)[64])(smem + 1024);
    int nl = t >> 6;
    int node = bid * 4 + nl;
    int d = t & 63;
    float v = ne[node * DD + d] + te[d];
    float s = v;
    #pragma unroll
    for (int m = 1; m < 64; m <<= 1) s += __shfl_xor(s, m, 64);
    float mu = s * (1.f / 64.f);
    float df = v - mu;
    float q = df * df;
    #pragma unroll
    for (int m = 1; m < 64; m <<= 1) q += __shfl_xor(q, m, 64);
    float rs = rsqrtf(q * (1.f / 64.f) + 1e-12f);
    float base = df * rs;
    float a = base * gg[d] + gb[d];
    float b = base * ug[d] + ub[d];
    egh[node * DD + d] = (f16)a;
    euh[node * DD + d] = (f16)b;
    esg[nl][d] = a; esu[nl][d] = b;
    __syncthreads();
    #pragma unroll
    for (int i = 0; i < 3; ++i) {
      int u = i * 256 + t;
      int un = u / 192, oo = u % 192;
      int n2 = bid * 4 + un;
      float acc = 0.f;
      if (oo < OG) {
        #pragma unroll 8
        for (int dd = 0; dd < 64; ++dd) acc += esg[un][dd] * gbp[dd * OG + oo];
        biasg[(size_t)n2 * OG + oo] = acc;
      } else {
        int o = oo - OG;
        #pragma unroll 8
        for (int dd = 0; dd < 64; ++dd) acc += esu[un][dd] * ubp[dd * OU + o];
        biasu[(size_t)n2 * OU + o] = acc;
      }
    }
  } else if (bid < 512 + 2304) {
    // ---------- wpool transpose: wt rows (ks*O+o)*32+kk, cols d ----------
    float (*tile)[17] = (float(*)[17])smem;
    const int t2 = bid - 512;
    const int ki = t2 % 192;
    const int oy = t2 / 192;           // 0..7 gate, 8..11 update
    const int upd = oy >= 8;
    const float* wpool = upd ? uwp : gwp;
    f16* wt = upd ? wtu : wtg;
    const int O = upd ? OU : OG;
    const int o0 = (upd ? oy - 8 : oy) * 16;
    const int ks = ki >> 5, kk = ki & 31;
    #pragma unroll
    for (int i = 0; i < 4; ++i) {
      int e2 = i * 256 + t;
      int d = e2 >> 4, o = e2 & 15;
      tile[d][o] = wpool[((size_t)d * KI + ki) * O + o0 + o];
    }
    __syncthreads();
    #pragma unroll
    for (int i = 0; i < 4; ++i) {
      int e2 = i * 256 + t;
      int o = e2 >> 6, d = e2 & 63;
      size_t row = ((size_t)ks * O + (o0 + o)) * 32 + kk;
      wt[row * DD + d] = (f16)tile[d][o];
    }
  } else {
    // ---------- build cm[b][c][m], xg (c<96), sth node-major ----------
    f16 (*tile)[66] = (f16(*)[66])smem;
    const int t2 = bid - 2816;
    const int mb = (t2 & 31) * 64;
    const int b = t2 >> 5;
    #pragma unroll
    for (int i = 0; i < 24; ++i) {
      int e2 = i * 256 + t;  // 0..6143
      int m = e2 / 96, c = e2 % 96;
      float v = (c < CINC) ? x[((size_t)b * NN + mb + m) * CINC + c]
                           : st[((size_t)b * NN + mb + m) * HH + c - CINC];
      f16 h = (f16)v;
      tile[c][m] = h;
      xg[XGI(mb + m, c >> 5, b, c & 31)] = h;
      if (c >= CINC) sth[STHI(mb + m, b, c - CINC)] = h;
    }
    __syncthreads();
    #pragma unroll
    for (int i = 0; i < 24; ++i) {
      int e2 = i * 256 + t;
      int c = e2 >> 6, m = e2 & 63;
      cm[((size_t)b * C1 + c) * NN + mb + m] = tile[c][m];
    }
  }
}

// ---------------- zs[b][m][o] -> cand_cm[b][32+o][m] ----------------
__global__ __launch_bounds__(256) void k_transpose_zs(const f16* __restrict__ zs,
                                                      f16* __restrict__ cm) {
  __shared__ f16 tile[64][66];
  int mb = blockIdx.x * 64;
  int b = blockIdx.y;
  int t = threadIdx.x;
  #pragma unroll
  for (int i = 0; i < 16; ++i) {
    int e2 = i * 256 + t;
    int m = e2 >> 6, o = e2 & 63;
    tile[o][m] = zs[((size_t)b * NN + mb + m) * HH + o];
  }
  __syncthreads();
  #pragma unroll
  for (int i = 0; i < 16; ++i) {
    int e2 = i * 256 + t;
    int o = e2 >> 6, m = e2 & 63;
    cm[((size_t)b * C1 + CINC + o) * NN + mb + m] = tile[o][m];
  }
}

// ------- fused scores+softmax (gate & update in one launch via blockIdx.y) -------
__global__ __launch_bounds__(256) void k_attn(const f16* __restrict__ eg,
                                              const f16* __restrict__ eu,
                                              f16* __restrict__ adjg,
                                              f16* __restrict__ adju) {
  const f16* eh = blockIdx.y ? eu : eg;
  f16* adj = blockIdx.y ? adju : adjg;
  const int r0 = blockIdx.x * 16;
  const int w = threadIdx.x >> 6, lane = threadIdx.x & 63;
  const int fr = lane & 15, fq = lane >> 4;
  __shared__ float pm[4][16], ps[4][16];
  __shared__ float fm[16], fs[16];
  const half8 a0 = *(const half8*)&eh[(size_t)(r0 + fr) * DD + fq * 8];
  const half8 a1 = *(const half8*)&eh[(size_t)(r0 + fr) * DD + 32 + fq * 8];
  float m[4], s[4];
  #pragma unroll
  for (int r = 0; r < 4; ++r) { m[r] = -3.0e38f; s[r] = 0.f; }
  for (int ct = 0; ct < 32; ++ct) {
    const int c0 = w * 512 + ct * 16;
    half8 b0 = *(const half8*)&eh[(size_t)(c0 + fr) * DD + fq * 8];
    half8 b1 = *(const half8*)&eh[(size_t)(c0 + fr) * DD + 32 + fq * 8];
    f32x4 d = mfma16(a0, b0, f32x4{0.f, 0.f, 0.f, 0.f});
    d = mfma16(a1, b1, d);
    #pragma unroll
    for (int r = 0; r < 4; ++r) {
      float mn = fmaxf(m[r], d[r]);
      s[r] = s[r] * __expf(m[r] - mn) + __expf(d[r] - mn);
      m[r] = mn;
    }
  }
  #pragma unroll
  for (int r = 0; r < 4; ++r) {
    #pragma unroll
    for (int mk = 1; mk < 16; mk <<= 1) {
      float mo = __shfl_xor(m[r], mk, 64);
      float so = __shfl_xor(s[r], mk, 64);
      float mn = fmaxf(m[r], mo);
      s[r] = s[r] * __expf(m[r] - mn) + so * __expf(mo - mn);
      m[r] = mn;
    }
  }
  if (fr == 0) {
    #pragma unroll
    for (int r = 0; r < 4; ++r) { pm[w][fq * 4 + r] = m[r]; ps[w][fq * 4 + r] = s[r]; }
  }
  __syncthreads();
  if (threadIdx.x < 16) {
    float M = -3.0e38f;
    #pragma unroll
    for (int i = 0; i < 4; ++i) M = fmaxf(M, pm[i][threadIdx.x]);
    float S = 0.f;
    #pragma unroll
    for (int i = 0; i < 4; ++i) S += ps[i][threadIdx.x] * __expf(pm[i][threadIdx.x] - M);
    fm[threadIdx.x] = M; fs[threadIdx.x] = 1.f / S;
  }
  __syncthreads();
  float Mr[4], Sr[4];
  #pragma unroll
  for (int r = 0; r < 4; ++r) { Mr[r] = fm[fq * 4 + r]; Sr[r] = fs[fq * 4 + r]; }
  for (int ct = 0; ct < 32; ++ct) {
    const int c0 = w * 512 + ct * 16;
    half8 b0 = *(const half8*)&eh[(size_t)(c0 + fr) * DD + fq * 8];
    half8 b1 = *(const half8*)&eh[(size_t)(c0 + fr) * DD + 32 + fq * 8];
    f32x4 d = mfma16(a0, b0, f32x4{0.f, 0.f, 0.f, 0.f});
    d = mfma16(a1, b1, d);
    #pragma unroll
    for (int r = 0; r < 4; ++r)
      adj[(size_t)(r0 + fq * 4 + r) * NN + c0 + fr] = (f16)(__expf(d[r] - Mr[r]) * Sr[r]);
  }
}

// ---------------- xa: xg (ki=96+l) = adj(n,m) @ cm(b*96+l, m)^T ----------------
#define BM 64
#define BN 96

__global__ __launch_bounds__(256, 4) void k_gemm_xa(const f16* __restrict__ A,
                                                    const f16* __restrict__ Bm,
                                                    f16* __restrict__ xg) {
  const int orig = blockIdx.x;          // 0..1023
  const int xcd = orig & 7, j = orig >> 3;
  const int nb = (j >> 2) * BM;
  const int by = (xcd << 2) + (j & 3);  // 4 consecutive by per XCD
  const int cb = by * BN;
  const int tid = threadIdx.x;
  const int w = tid >> 6, lane = tid & 63;
  const int wr = (w >> 1) * 32, wc = (w & 1) * 48;
  const int fr = lane & 15, fq = lane >> 4;

  const int arow = tid >> 3;                               // 0..31
  const int acolb = ((tid & 7) * 16) ^ ((arow & 7) << 4);  // pre-swizzled, j-invariant
  const char* asrc = (const char*)A + (size_t)(nb + arow) * (NN * 2) + acolb;
  const char* bsrc = (const char*)Bm + (size_t)(cb + arow) * (NN * 2) + acolb;

  __shared__ f16 Al[2][BM * 64];
  __shared__ f16 Bl[2][BN * 64];
  auto stage = [&](int buf, int kt) {   // 5 x global_load_lds per wave
    const size_t ko = (size_t)kt * 2;
    char* ad = (char*)&Al[buf][0] + (w << 10);
    char* bd = (char*)&Bl[buf][0] + (w << 10);
    gl_lds16(asrc + ko, ad);
    gl_lds16(asrc + ko + (size_t)32 * (NN * 2), ad + 4096);
    gl_lds16(bsrc + ko, bd);
    gl_lds16(bsrc + ko + (size_t)32 * (NN * 2), bd + 4096);
    gl_lds16(bsrc + ko + (size_t)64 * (NN * 2), bd + 8192);
  };

  f32x4 acc[2][3] = {};
  stage(0, 0);
  for (int kt = 0; kt < NN; kt += 64) {
    const int cur = (kt >> 6) & 1;
    if (kt + 64 < NN) {
      stage(cur ^ 1, kt + 64);
      asm volatile("s_waitcnt vmcnt(5)" ::: "memory");   // my stage(cur) landed
    } else {
      asm volatile("s_waitcnt vmcnt(0)" ::: "memory");
    }
    __builtin_amdgcn_sched_barrier(0);
    __builtin_amdgcn_s_barrier();                         // A: buf[cur] ready (all waves)
    const char* Ab = (const char*)&Al[cur][0];
    const char* Bb = (const char*)&Bl[cur][0];
    half8 af[2][2], bf[2][3];
    #pragma unroll
    for (int k0 = 0; k0 < 2; ++k0) {
      const int kb = k0 * 64 + fq * 16;
      #pragma unroll
      for (int mt = 0; mt < 2; ++mt)
        af[k0][mt] = *(const half8*)(Ab + SWZ(wr + mt * 16 + fr, kb));
      #pragma unroll
      for (int nt = 0; nt < 3; ++nt)
        bf[k0][nt] = *(const half8*)(Bb + SWZ(wc + nt * 16 + fr, kb));
    }
    asm volatile("s_waitcnt lgkmcnt(0)" ::: "memory");    // my reads of buf[cur] done
    __builtin_amdgcn_sched_barrier(0);
    __builtin_amdgcn_s_barrier();                         // B: release buf[cur] for restage
    #pragma unroll
    for (int k0 = 0; k0 < 2; ++k0)
      #pragma unroll
      for (int mt = 0; mt < 2; ++mt)
        #pragma unroll
        for (int nt = 0; nt < 3; ++nt)
          acc[mt][nt] = mfma16(af[k0][mt], bf[k0][nt], acc[mt][nt]);
  }
  #pragma unroll
  for (int mt = 0; mt < 2; ++mt)
    #pragma unroll
    for (int nt = 0; nt < 3; ++nt)
      #pragma unroll
      for (int r = 0; r < 4; ++r) {
        int n = nb + wr + mt * 16 + fq * 4 + r;
        int l = wc + nt * 16 + fr;         // 0..95 -> ki = 96+l
        xg[XGI(n, 3 + (l >> 5), by, l & 31)] = (f16)acc[mt][nt][r];
      }
}

// ---------------- W(all nodes): W[n][c] = e(n,:) . wt(c, :), c = (ks*O+o)*32+kk ----------------
__global__ __launch_bounds__(256) void k_gemm_w2(const f16* __restrict__ A,
                                                 const f16* __restrict__ B,
                                                 f16* __restrict__ W, int ncols) {
  __shared__ f16 Al[128 * 64];
  __shared__ f16 Bl[128 * 64];
  const int cb = blockIdx.x * 128;
  const int nb = blockIdx.y * 128;
  const int tid = threadIdx.x;
  const int w = tid >> 6, lane = tid & 63;
  const int wr = (w >> 1) * 64, wc = (w & 1) * 64;
  const int fr = lane & 15, fq = lane >> 4;
  const int arow = tid >> 3;
  const int acolb = ((tid & 7) * 16) ^ ((arow & 7) << 4);
  const char* asrc = (const char*)A + (size_t)(nb + arow) * 128 + acolb;
  const char* bsrc = (const char*)B + (size_t)(cb + arow) * 128 + acolb;
  char* ad = (char*)Al + (w << 10);
  char* bd = (char*)Bl + (w << 10);
  #pragma unroll
  for (int j = 0; j < 4; ++j) gl_lds16(asrc + (size_t)j * 32 * 128, ad + j * 4096);
  #pragma unroll
  for (int j = 0; j < 4; ++j) gl_lds16(bsrc + (size_t)j * 32 * 128, bd + j * 4096);
  __syncthreads();
  f32x4 acc[4][4] = {};
  #pragma unroll
  for (int k0 = 0; k0 < 2; ++k0) {
    const int kb = k0 * 64 + fq * 16;
    half8 af[4], bf[4];
    #pragma unroll
    for (int mt = 0; mt < 4; ++mt)
      af[mt] = *(const half8*)((const char*)Al + SWZ(wr + mt * 16 + fr, kb));
    #pragma unroll
    for (int nt = 0; nt < 4; ++nt)
      bf[nt] = *(const half8*)((const char*)Bl + SWZ(wc + nt * 16 + fr, kb));
    #pragma unroll
    for (int mt = 0; mt < 4; ++mt)
      #pragma unroll
      for (int nt = 0; nt < 4; ++nt)
        acc[mt][nt] = mfma16(af[mt], bf[nt], acc[mt][nt]);
  }
  #pragma unroll
  for (int mt = 0; mt < 4; ++mt)
    #pragma unroll
    for (int nt = 0; nt < 4; ++nt)
      #pragma unroll
      for (int r = 0; r < 4; ++r) {
        int n = nb + wr + mt * 16 + fq * 4 + r;
        int c = cb + wc + nt * 16 + fr;
        W[(size_t)n * ncols + c] = (f16)acc[mt][nt][r];
      }
}

// ---------------- apply: out(b,n,o) = xg(n,b,:) . W[n](o,:) + bias, + epilogues ----------------
// W layout: [n][(ks*O+o)*32+kk]; xg layout: [n][ks][b][kk] -> 1KB-contiguous wave loads.
// sth/rbuf node-major [n][b][h] -> per-block 4KB locality on both sides.
template <bool GATE>
__global__ __launch_bounds__(256) void k_apply3(
    const f16* __restrict__ xg, const f16* __restrict__ W,
    const float* __restrict__ bias,
    const f16* __restrict__ sth,
    f16* xgw, f16* __restrict__ zs, f16* __restrict__ rbuf,
    float* __restrict__ outp) {
  constexpr int O = GATE ? OG : OU;
  constexpr int WS = GATE ? WCG : WCU;
  constexpr int NOT_ = GATE ? 2 : 1;
  const int n = blockIdx.x;
  const int lane = threadIdx.x & 63, w = threadIdx.x >> 6;
  const int fr = lane & 15, fq = lane >> 4;
  half8 af[2][6];
  #pragma unroll
  for (int mt = 0; mt < 2; ++mt) {
    #pragma unroll
    for (int ks = 0; ks < 6; ++ks)
      af[mt][ks] = *(const half8*)&xg[XGI(n, ks, mt * 16 + fr, fq * 8)];
  }
  if (GATE) __syncthreads();  // all A reads before z-slice writes to xg
  f32x4 acc[2][NOT_] = {};
  #pragma unroll
  for (int ks = 0; ks < 6; ++ks) {
    #pragma unroll
    for (int ot = 0; ot < NOT_; ++ot) {
      int o = (GATE ? (w * 2 + ot) : w) * 16 + fr;
      half8 bf = *(const half8*)&W[(size_t)n * WS + (((size_t)ks * O + o) << 5) + fq * 8];
      #pragma unroll
      for (int mt = 0; mt < 2; ++mt) acc[mt][ot] = mfma16(af[mt][ks], bf, acc[mt][ot]);
    }
  }
  #pragma unroll
  for (int mt = 0; mt < 2; ++mt)
    #pragma unroll
    for (int ot = 0; ot < NOT_; ++ot) {
      const int o = (GATE ? (w * 2 + ot) : w) * 16 + fr;
      const float bs = bias[(size_t)n * O + o];
      #pragma unroll
      for (int r = 0; r < 4; ++r) {
        int b = mt * 16 + fq * 4 + r;
        float val = acc[mt][ot][r] + bs;
        if (GATE) {
          float s = 1.f / (1.f + expf(-val));
          if (o < HH) {
            float zst = s * (float)sth[STHI(n, b, o)];
            xgw[XGI(n, 1 + (o >> 5), b, o & 31)] = (f16)zst;  // ki = 32+o
            zs[((size_t)b * NN + n) * HH + o] = (f16)zst;
          } else {
            rbuf[STHI(n, b, o - HH)] = (f16)s;
          }
        } else {
          float hc = tanhf(val);
          float rr = (float)rbuf[STHI(n, b, o)];
          outp[((size_t)b * NN + n) * HH + o] =
              rr * (float)sth[STHI(n, b, o)] + (1.f - rr) * hc;
        }
      }
    }
}

extern "C" void kernel_launch(void* const* d_in, const int* in_sizes, int n_in,
                              void* d_out, int out_size, void* d_ws, size_t ws_size,
                              hipStream_t stream) {
  const float* x   = (const float*)d_in[0];
  const float* st  = (const float*)d_in[1];
  const float* ne  = (const float*)d_in[2];
  const float* te  = (const float*)d_in[3];
  const float* gwp = (const float*)d_in[4];
  const float* gbp = (const float*)d_in[5];
  const float* gg  = (const float*)d_in[6];
  const float* gb  = (const float*)d_in[7];
  const float* uwp = (const float*)d_in[8];
  const float* ubp = (const float*)d_in[9];
  const float* ug  = (const float*)d_in[10];
  const float* ub  = (const float*)d_in[11];
  float* out = (float*)d_out;

  char* wsb = (char*)d_ws;
  size_t off = 0;
  auto alloc = [&](size_t bytes) {
    char* p = wsb + off;
    off = (off + bytes + 255) & ~(size_t)255;
    return p;
  };
  f16*   egh   = (f16*)  alloc((size_t)NN * DD * 2);
  f16*   euh   = (f16*)  alloc((size_t)NN * DD * 2);
  float* biasg = (float*)alloc((size_t)NN * OG * 4);
  float* biasu = (float*)alloc((size_t)NN * OU * 4);
  f16*   wtg   = (f16*)  alloc((size_t)WCG * DD * 2);       //  3 MB
  f16*   wtu   = (f16*)  alloc((size_t)WCU * DD * 2);       // 1.5 MB
  f16*   xg    = (f16*)  alloc((size_t)NN * BB * KI * 2);   // 24 MB
  f16*   cm    = (f16*)  alloc((size_t)BB * C1 * NN * 2);   // 12 MB
  f16*   zs    = (f16*)  alloc((size_t)BB * NN * HH * 2);   //  8 MB
  f16*   rbuf  = (f16*)  alloc((size_t)BB * NN * HH * 2);   //  8 MB
  f16*   sth   = (f16*)  alloc((size_t)BB * NN * HH * 2);   //  8 MB
  f16*   adj   = (f16*)  alloc((size_t)NN * NN * 2);        //  8 MB
  f16*   adju  = (f16*)  alloc((size_t)NN * NN * 2);        //  8 MB
  f16*   W     = (f16*)  alloc((size_t)NN * WCG * 2);       // 96 MB
  (void)ws_size; (void)in_sizes; (void)n_in; (void)out_size;

  hipLaunchKernelGGL(k_prep, dim3(512 + 2304 + 1024), dim3(256), 0, stream,
                     ne, te, gg, gb, ug, ub, gbp, ubp, gwp, uwp, x, st,
                     egh, euh, biasg, biasu, wtg, wtu, cm, xg, sth);
  hipLaunchKernelGGL(k_attn, dim3(NN / 16, 2), dim3(256), 0, stream,
                     egh, euh, adj, adju);

  // ---- gate GCN ----
  hipLaunchKernelGGL(k_gemm_xa, dim3(1024), dim3(256), 0, stream, adj, cm, xg);
  hipLaunchKernelGGL(k_gemm_w2, dim3(WCG / 128, NN / 128), dim3(256), 0, stream,
                     egh, wtg, W, WCG);
  hipLaunchKernelGGL((k_apply3<true>), dim3(NN), dim3(256), 0, stream,
                     xg, W, biasg, sth, xg, zs, rbuf, (float*)nullptr);
  hipLaunchKernelGGL(k_transpose_zs, dim3(NN / 64, BB), dim3(256), 0, stream, zs, cm);

  // ---- update GCN ----
  hipLaunchKernelGGL(k_gemm_xa, dim3(1024), dim3(256), 0, stream, adju, cm, xg);
  hipLaunchKernelGGL(k_gemm_w2, dim3(WCU / 128, NN / 128), dim3(256), 0, stream,
                     euh, wtu, W, WCU);
  hipLaunchKernelGGL((k_apply3<false>), dim3(NN), dim3(256), 0, stream,
                     xg, W, biasu, sth, (f16*)nullptr, (f16*)nullptr, rbuf, out);
}